// Round 1
// baseline (1071.808 us; speedup 1.0000x reference)
//
#include <hip/hip_runtime.h>
#include <math.h>

// GCN(1->16) -> lrelu -> GCN(16->1) -> lrelu -> FC(100000->1024)+lrelu
// -> FC(1024->256) -> log_softmax.
// Key reduction: conv layers collapse to SCALAR per-node scatters because
// in_ch=1 (conv1, rank-1 W) and out_ch=1 (conv2).

constexpr int NN   = 100000;
constexpr int NE   = 3200000;
constexpr int CONVC = 16;
constexpr int HID  = 1024;
constexpr int NOUT = 256;
#define NEG 0.01f

__device__ __forceinline__ float lrelu(float x) { return x >= 0.0f ? x : NEG * x; }

__device__ __forceinline__ float wave_reduce_sum(float v) {
#pragma unroll
  for (int off = 32; off > 0; off >>= 1) v += __shfl_down(v, off, 64);
  return v;
}

// deg starts at 1.0 (self-loop)
__global__ __launch_bounds__(256) void k_init_deg(float* __restrict__ deg) {
  int i = blockIdx.x * 256 + threadIdx.x;
  if (i < NN) deg[i] = 1.0f;
}

__global__ __launch_bounds__(256) void k_deg(const int* __restrict__ dst,
                                             float* __restrict__ deg) {
  int i = blockIdx.x * 256 + threadIdx.x;
  if (i < NE / 4) {
    int4 d4 = reinterpret_cast<const int4*>(dst)[i];
    atomicAdd(&deg[d4.x], 1.0f);
    atomicAdd(&deg[d4.y], 1.0f);
    atomicAdd(&deg[d4.z], 1.0f);
    atomicAdd(&deg[d4.w], 1.0f);
  }
}

// dinv = rsqrt(deg) in-place; p = self-loop contribution x*dinv^2
__global__ __launch_bounds__(256) void k_dinv_p(const float* __restrict__ x,
                                                float* __restrict__ dinv_io,
                                                float* __restrict__ p) {
  int i = blockIdx.x * 256 + threadIdx.x;
  if (i < NN) {
    float di = rsqrtf(dinv_io[i]);  // deg >= 1 always
    dinv_io[i] = di;
    p[i] = x[i] * di * di;
  }
}

// acc[d] += val[s] * dinv[s] * dinv[d]   (scalar GCN message pass)
__global__ __launch_bounds__(256) void k_scatter(const int* __restrict__ src,
                                                 const int* __restrict__ dst,
                                                 const float* __restrict__ val,
                                                 const float* __restrict__ dinv,
                                                 float* __restrict__ acc) {
  int i = blockIdx.x * 256 + threadIdx.x;
  if (i < NE / 4) {
    int4 s4 = reinterpret_cast<const int4*>(src)[i];
    int4 d4 = reinterpret_cast<const int4*>(dst)[i];
    atomicAdd(&acc[d4.x], val[s4.x] * dinv[s4.x] * dinv[d4.x]);
    atomicAdd(&acc[d4.y], val[s4.y] * dinv[s4.y] * dinv[d4.y]);
    atomicAdd(&acc[d4.z], val[s4.z] * dinv[s4.z] * dinv[d4.z]);
    atomicAdd(&acc[d4.w], val[s4.w] * dinv[s4.w] * dinv[d4.w]);
  }
}

// q[i] = sum_c lrelu(p[i]*W1[c]+b1[c]) * W2[c];  r seeded with self-loop q*dinv^2
__global__ __launch_bounds__(256) void k_q(const float* __restrict__ p,
                                           const float* __restrict__ dinv,
                                           const float* __restrict__ W1,
                                           const float* __restrict__ b1,
                                           const float* __restrict__ W2,
                                           float* __restrict__ q,
                                           float* __restrict__ r) {
  int i = blockIdx.x * 256 + threadIdx.x;
  if (i < NN) {
    float pv = p[i];
    float s = 0.0f;
#pragma unroll
    for (int c = 0; c < CONVC; c++) s += lrelu(pv * W1[c] + b1[c]) * W2[c];
    q[i] = s;
    float di = dinv[i];
    r[i] = s * di * di;
  }
}

// z[row] = lrelu( dot(Wf1[row,:], lrelu(r + b2)) + bf1[row] ) ; one block/row
__global__ __launch_bounds__(256) void k_mv1(const float* __restrict__ Wf1,
                                             const float* __restrict__ r,
                                             const float* __restrict__ b2c,
                                             const float* __restrict__ bf1,
                                             float* __restrict__ z) {
  int row = blockIdx.x;
  const float4* w4 = reinterpret_cast<const float4*>(Wf1 + (size_t)row * NN);
  const float4* r4 = reinterpret_cast<const float4*>(r);
  float b2 = b2c[0];
  float sum = 0.0f;
  for (int j = threadIdx.x; j < NN / 4; j += 256) {
    float4 w = w4[j];
    float4 rv = r4[j];
    sum += w.x * lrelu(rv.x + b2) + w.y * lrelu(rv.y + b2) +
           w.z * lrelu(rv.z + b2) + w.w * lrelu(rv.w + b2);
  }
  sum = wave_reduce_sum(sum);
  __shared__ float ss[4];
  if ((threadIdx.x & 63) == 0) ss[threadIdx.x >> 6] = sum;
  __syncthreads();
  if (threadIdx.x == 0) {
    float t = ss[0] + ss[1] + ss[2] + ss[3];
    z[row] = lrelu(t + bf1[row]);
  }
}

// tmp[o] = dot(Wf2[o,:], z) + bf2[o] ; one block per output, HID/4==256 exactly
__global__ __launch_bounds__(256) void k_mv2(const float* __restrict__ Wf2,
                                             const float* __restrict__ z,
                                             const float* __restrict__ bf2,
                                             float* __restrict__ tmp) {
  int o = blockIdx.x;
  const float4* w4 = reinterpret_cast<const float4*>(Wf2 + (size_t)o * HID);
  const float4* z4 = reinterpret_cast<const float4*>(z);
  int j = threadIdx.x;
  float4 w = w4[j];
  float4 zv = z4[j];
  float sum = w.x * zv.x + w.y * zv.y + w.z * zv.z + w.w * zv.w;
  sum = wave_reduce_sum(sum);
  __shared__ float ss[4];
  if ((threadIdx.x & 63) == 0) ss[threadIdx.x >> 6] = sum;
  __syncthreads();
  if (threadIdx.x == 0) tmp[o] = ss[0] + ss[1] + ss[2] + ss[3] + bf2[o];
}

// log_softmax over 256 values, single block
__global__ __launch_bounds__(256) void k_lsm(const float* __restrict__ tmp,
                                             float* __restrict__ out) {
  int t = threadIdx.x;
  float v = tmp[t];
  __shared__ float buf[256];
  buf[t] = v;
  __syncthreads();
  for (int s = 128; s > 0; s >>= 1) {
    if (t < s) buf[t] = fmaxf(buf[t], buf[t + s]);
    __syncthreads();
  }
  float m = buf[0];
  __syncthreads();
  buf[t] = expf(v - m);
  __syncthreads();
  for (int s = 128; s > 0; s >>= 1) {
    if (t < s) buf[t] += buf[t + s];
    __syncthreads();
  }
  float lse = logf(buf[0]);
  out[t] = v - m - lse;
}

extern "C" void kernel_launch(void* const* d_in, const int* in_sizes, int n_in,
                              void* d_out, int out_size, void* d_ws, size_t ws_size,
                              hipStream_t stream) {
  const float* x   = (const float*)d_in[0];
  const int*   ei  = (const int*)d_in[1];  // [2, E] row-major: src then dst
  const float* W1c = (const float*)d_in[2];
  const float* b1c = (const float*)d_in[3];
  const float* W2c = (const float*)d_in[4];
  const float* b2c = (const float*)d_in[5];
  const float* Wf1 = (const float*)d_in[6];
  const float* bf1 = (const float*)d_in[7];
  const float* Wf2 = (const float*)d_in[8];
  const float* bf2 = (const float*)d_in[9];
  float* out = (float*)d_out;

  const int* src = ei;
  const int* dst = ei + NE;

  // ws layout (fp32): dinv | p | q | r | z | tmp  (~1.6 MB, re-poisoned each call
  // so every buffer is written before read: deg init kernel seeds dinv)
  float* ws   = (float*)d_ws;
  float* dinv = ws;
  float* p    = ws + (size_t)NN;
  float* q    = ws + (size_t)2 * NN;
  float* r    = ws + (size_t)3 * NN;
  float* z    = ws + (size_t)4 * NN;
  float* tmp  = z + HID;

  int nb_n = (NN + 255) / 256;
  int nb_e = (NE / 4 + 255) / 256;

  k_init_deg<<<nb_n, 256, 0, stream>>>(dinv);
  k_deg<<<nb_e, 256, 0, stream>>>(dst, dinv);
  k_dinv_p<<<nb_n, 256, 0, stream>>>(x, dinv, p);
  k_scatter<<<nb_e, 256, 0, stream>>>(src, dst, x, dinv, p);
  k_q<<<nb_n, 256, 0, stream>>>(p, dinv, W1c, b1c, W2c, q, r);
  k_scatter<<<nb_e, 256, 0, stream>>>(src, dst, q, dinv, r);
  k_mv1<<<HID, 256, 0, stream>>>(Wf1, r, b2c, bf1, z);
  k_mv2<<<NOUT, 256, 0, stream>>>(Wf2, z, bf2, tmp);
  k_lsm<<<1, 256, 0, stream>>>(tmp, out);
}

// Round 2
// 864.231 us; speedup vs baseline: 1.2402x; 1.2402x over previous
//
#include <hip/hip_runtime.h>
#include <math.h>

// GCN(1->16) -> lrelu -> GCN(16->1) -> lrelu -> FC(100000->1024)+lrelu
// -> FC(1024->256) -> log_softmax.
// R2: global atomics (3 passes x 3.2M, measured ~11 G atomic/s => ~900us)
// replaced by node-partitioned LDS binning + plain-store partials + column
// reduce. Norm factored: S[j] = sum_{e:d=j} xs[s], xs = x*dinv; dinv[j]
// applied in the epilogue (1 random gather per edge instead of 3).

constexpr int NN    = 100000;
constexpr int NE    = 3200000;
constexpr int CONVC = 16;
constexpr int HID   = 1024;
constexpr int NOUT  = 256;
constexpr int P     = 8;      // node partitions
constexpr int PART  = 12800;  // nodes per partition (50 KB LDS -> 3 blocks/CU)
constexpr int C     = 96;     // edge chunks
constexpr int CHUNK = 33334;  // ceil(NE/C)
#define NEG 0.01f

__device__ __forceinline__ float lrelu(float x) { return x >= 0.0f ? x : NEG * x; }

__device__ __forceinline__ float wave_reduce_sum(float v) {
#pragma unroll
  for (int off = 32; off > 0; off >>= 1) v += __shfl_down(v, off, 64);
  return v;
}

// ---- binned degree count: partial[c][j] = #edges in chunk c with dst==j ----
__global__ __launch_bounds__(256) void k_bin_deg(const int* __restrict__ dst,
                                                 float* __restrict__ partial) {
  __shared__ float acc[PART];
  int c = blockIdx.x, p = blockIdx.y;
  for (int i = threadIdx.x; i < PART; i += 256) acc[i] = 0.0f;
  __syncthreads();
  int base = c * CHUNK;
  int lim = min(CHUNK, NE - base);
  int lo = p * PART;
  for (int e = threadIdx.x; e < lim; e += 256) {
    int d = dst[base + e];
    unsigned local = (unsigned)(d - lo);
    if (local < (unsigned)PART) atomicAdd(&acc[local], 1.0f);
  }
  __syncthreads();
  float* out = partial + (size_t)c * NN;
  int hi = min(lo + PART, NN);
  for (int j = lo + threadIdx.x; j < hi; j += 256) out[j] = acc[j - lo];
}

// ---- binned scatter: partial[c][j] = sum over chunk-c edges (dst==j) of val[src] ----
__global__ __launch_bounds__(256) void k_bin_scat(const int* __restrict__ src,
                                                  const int* __restrict__ dst,
                                                  const float* __restrict__ val,
                                                  float* __restrict__ partial) {
  __shared__ float acc[PART];
  int c = blockIdx.x, p = blockIdx.y;
  for (int i = threadIdx.x; i < PART; i += 256) acc[i] = 0.0f;
  __syncthreads();
  int base = c * CHUNK;
  int lim = min(CHUNK, NE - base);
  int lo = p * PART;
  for (int e = threadIdx.x; e < lim; e += 256) {
    int d = dst[base + e];
    unsigned local = (unsigned)(d - lo);
    if (local < (unsigned)PART) {
      int s = src[base + e];
      atomicAdd(&acc[local], val[s]);
    }
  }
  __syncthreads();
  float* out = partial + (size_t)c * NN;
  int hi = min(lo + PART, NN);
  for (int j = lo + threadIdx.x; j < hi; j += 256) out[j] = acc[j - lo];
}

// ---- reduce deg partials -> dinv, xs = x*dinv ----
__global__ __launch_bounds__(256) void k_red_dinv(const float* __restrict__ partial,
                                                  const float* __restrict__ x,
                                                  float* __restrict__ dinv,
                                                  float* __restrict__ xs) {
  int i = blockIdx.x * 256 + threadIdx.x;
  if (i >= NN) return;
  float s = 1.0f;  // self-loop
#pragma unroll 4
  for (int c = 0; c < C; c++) s += partial[(size_t)c * NN + i];
  float di = rsqrtf(s);
  dinv[i] = di;
  xs[i] = x[i] * di;
}

// ---- reduce scatter1 partials -> p (conv1 pre-act), q (conv2 input), xs2=q*dinv ----
__global__ __launch_bounds__(256) void k_red_q(const float* __restrict__ partial,
                                               const float* __restrict__ x,
                                               const float* __restrict__ dinv,
                                               const float* __restrict__ W1,
                                               const float* __restrict__ b1,
                                               const float* __restrict__ W2,
                                               float* __restrict__ qv,
                                               float* __restrict__ xs2) {
  int i = blockIdx.x * 256 + threadIdx.x;
  if (i >= NN) return;
  float s = 0.0f;
#pragma unroll 4
  for (int c = 0; c < C; c++) s += partial[(size_t)c * NN + i];
  float di = dinv[i];
  float pv = di * (s + x[i] * di);  // conv1 scalar factor (incl. self-loop)
  float q = 0.0f;
#pragma unroll
  for (int ch = 0; ch < CONVC; ch++) q += lrelu(pv * W1[ch] + b1[ch]) * W2[ch];
  qv[i] = q;
  xs2[i] = q * di;
}

// ---- reduce scatter2 partials -> v = lrelu(conv2 out) ----
__global__ __launch_bounds__(256) void k_red_v(const float* __restrict__ partial,
                                               const float* __restrict__ qv,
                                               const float* __restrict__ dinv,
                                               const float* __restrict__ b2c,
                                               float* __restrict__ v) {
  int i = blockIdx.x * 256 + threadIdx.x;
  if (i >= NN) return;
  float s = 0.0f;
#pragma unroll 4
  for (int c = 0; c < C; c++) s += partial[(size_t)c * NN + i];
  float di = dinv[i];
  float r = di * (s + qv[i] * di) + b2c[0];
  v[i] = lrelu(r);
}

// ---- z[row] = lrelu(dot(Wf1[row,:], v) + bf1[row]); one block per row ----
__global__ __launch_bounds__(256) void k_mv1(const float* __restrict__ Wf1,
                                             const float* __restrict__ v,
                                             const float* __restrict__ bf1,
                                             float* __restrict__ z) {
  int row = blockIdx.x;
  const float4* w4 = reinterpret_cast<const float4*>(Wf1 + (size_t)row * NN);
  const float4* v4 = reinterpret_cast<const float4*>(v);
  float sum = 0.0f;
  for (int j = threadIdx.x; j < NN / 4; j += 256) {
    float4 w = w4[j];
    float4 vv = v4[j];
    sum += w.x * vv.x + w.y * vv.y + w.z * vv.z + w.w * vv.w;
  }
  sum = wave_reduce_sum(sum);
  __shared__ float ss[4];
  if ((threadIdx.x & 63) == 0) ss[threadIdx.x >> 6] = sum;
  __syncthreads();
  if (threadIdx.x == 0) z[row] = lrelu(ss[0] + ss[1] + ss[2] + ss[3] + bf1[row]);
}

// ---- tmp[o] = dot(Wf2[o,:], z) + bf2[o]; HID/4 == 256 threads exactly ----
__global__ __launch_bounds__(256) void k_mv2(const float* __restrict__ Wf2,
                                             const float* __restrict__ z,
                                             const float* __restrict__ bf2,
                                             float* __restrict__ tmp) {
  int o = blockIdx.x;
  const float4* w4 = reinterpret_cast<const float4*>(Wf2 + (size_t)o * HID);
  const float4* z4 = reinterpret_cast<const float4*>(z);
  int j = threadIdx.x;
  float4 w = w4[j];
  float4 zv = z4[j];
  float sum = w.x * zv.x + w.y * zv.y + w.z * zv.z + w.w * zv.w;
  sum = wave_reduce_sum(sum);
  __shared__ float ss[4];
  if ((threadIdx.x & 63) == 0) ss[threadIdx.x >> 6] = sum;
  __syncthreads();
  if (threadIdx.x == 0) tmp[o] = ss[0] + ss[1] + ss[2] + ss[3] + bf2[o];
}

// ---- log_softmax over 256 values, single block ----
__global__ __launch_bounds__(256) void k_lsm(const float* __restrict__ tmp,
                                             float* __restrict__ out) {
  int t = threadIdx.x;
  float vv = tmp[t];
  __shared__ float buf[256];
  buf[t] = vv;
  __syncthreads();
  for (int s = 128; s > 0; s >>= 1) {
    if (t < s) buf[t] = fmaxf(buf[t], buf[t + s]);
    __syncthreads();
  }
  float m = buf[0];
  __syncthreads();
  buf[t] = expf(vv - m);
  __syncthreads();
  for (int s = 128; s > 0; s >>= 1) {
    if (t < s) buf[t] += buf[t + s];
    __syncthreads();
  }
  float lse = logf(buf[0]);
  out[t] = vv - m - lse;
}

extern "C" void kernel_launch(void* const* d_in, const int* in_sizes, int n_in,
                              void* d_out, int out_size, void* d_ws, size_t ws_size,
                              hipStream_t stream) {
  const float* x   = (const float*)d_in[0];
  const int*   ei  = (const int*)d_in[1];  // [2, E]: src row then dst row (int32)
  const float* W1c = (const float*)d_in[2];
  const float* b1c = (const float*)d_in[3];
  const float* W2c = (const float*)d_in[4];
  const float* b2c = (const float*)d_in[5];
  const float* Wf1 = (const float*)d_in[6];
  const float* bf1 = (const float*)d_in[7];
  const float* Wf2 = (const float*)d_in[8];
  const float* bf2 = (const float*)d_in[9];
  float* out = (float*)d_out;

  const int* src = ei;
  const int* dst = ei + NE;

  // ws: partial[C][NN] | dinv | xs | qv | xs2 | v | z | tmp  (~40 MB)
  float* ws      = (float*)d_ws;
  float* partial = ws;
  float* dinv    = partial + (size_t)C * NN;
  float* xs      = dinv + NN;
  float* qv      = xs + NN;
  float* xs2     = qv + NN;
  float* v       = xs2 + NN;
  float* z       = v + NN;
  float* tmp     = z + HID;

  dim3 bins(C, P);
  int nb_n = (NN + 255) / 256;

  k_bin_deg<<<bins, 256, 0, stream>>>(dst, partial);
  k_red_dinv<<<nb_n, 256, 0, stream>>>(partial, x, dinv, xs);
  k_bin_scat<<<bins, 256, 0, stream>>>(src, dst, xs, partial);
  k_red_q<<<nb_n, 256, 0, stream>>>(partial, x, dinv, W1c, b1c, W2c, qv, xs2);
  k_bin_scat<<<bins, 256, 0, stream>>>(src, dst, xs2, partial);
  k_red_v<<<nb_n, 256, 0, stream>>>(partial, qv, dinv, b2c, v);
  k_mv1<<<HID, 256, 0, stream>>>(Wf1, v, bf1, z);
  k_mv2<<<NOUT, 256, 0, stream>>>(Wf2, z, bf2, tmp);
  k_lsm<<<1, 256, 0, stream>>>(tmp, out);
}